// Round 6
// baseline (965.485 us; speedup 1.0000x reference)
//
#include <hip/hip_runtime.h>
#include <math.h>

// Problem constants (reference: H=256, N=32, S=256, R=1, CCH=32, L=2048, B=2)
#define LF   1025     // L/2+1

// ---- workspace layout (bytes) ----
// (TW region @0 retired - twiddles now computed via v_sin/v_cos in-register)
#define OFF_ZT   65536
#define OFF_KF   131072
#define OFF_PDF  67371008
#define OFF_DCT  84148224

__device__ __forceinline__ float2 cmulf(float2 a, float2 b){
    return make_float2(a.x*b.x - a.y*b.y, a.x*b.y + a.y*b.x);
}
// LDS padding: 1 extra float2 per 16 -> breaks power-of-2 bank aliasing of the
// Stockham scatter.
__device__ __forceinline__ int pidx(int i){ return i + (i >> 4); }

// e^{-2 pi i r}, 0 <= r < 1 (exact dyadic). v_sin/v_cos take REVOLUTIONS on
// gfx9xx -> no table, no gather, no range reduction needed.
__device__ __forceinline__ float2 twid(float r){
    float s, c;
    asm("v_sin_f32 %0, %1" : "=v"(s) : "v"(r));
    asm("v_cos_f32 %0, %1" : "=v"(c) : "v"(r));
    return make_float2(c, -s);
}

// ---------------- init: bilinear nodes (fp64 once) ----------------
__global__ void initk(float4* __restrict__ ZT){
    int i = blockIdx.x*256 + threadIdx.x;
    if (i < LF){
        double th = (-2.0*M_PI) * (double)i / 2048.0;
        double cr = cos(th), ci = sin(th);
        double ar = 1.0 + cr, ai = ci;              // 1+w
        double den = ar*ar + ai*ai;
        double nr = 1.0 - cr, ni = -ci;             // 1-w
        double zr = 2.0*(nr*ar + ni*ai)/den;        // z = 2(1-w)/(1+w)
        double zi = 2.0*(ni*ar - nr*ai)/den;
        ZT[i] = make_float4((float)zr, (float)zi, (float)(2.0*ar/den), (float)(-2.0*ai/den));
    }
}

// ---------------- dC (l, h, c) -> DCT (h*32+c, l) ----------------
__global__ void transpose_dC(const float* __restrict__ dC, float* __restrict__ DCT){
    __shared__ float tile[32][33];
    int hc0 = blockIdx.x*32;
    int l0  = blockIdx.y*32;
    int tx = threadIdx.x;
    for (int i = threadIdx.y; i < 32; i += 8)
        tile[i][tx] = dC[(size_t)(l0+i)*8192 + hc0 + tx];
    __syncthreads();
    for (int i = threadIdx.y; i < 32; i += 8)
        DCT[(size_t)(hc0+i)*2048 + l0 + tx] = tile[tx][i];
}

// ---------------- Cauchy + Woodbury -> k_f ---------------- (unchanged, passes)
__global__ __launch_bounds__(256) void cauchy_k(
                         const float* __restrict__ log_dt, const float* __restrict__ B_ri,
                         const float* __restrict__ P_ri, const float* __restrict__ C_ri,
                         const float* __restrict__ ivw, const float* __restrict__ wimag,
                         const float4* __restrict__ ZT, float2* __restrict__ KF)
{
    const int h  = blockIdx.y;
    const int c0 = blockIdx.z * 8;
    const int l  = blockIdx.x*256 + (int)threadIdx.x;
    __shared__ float wre[32], wim[32], bre[32], bim[32], ppre[32], ppim[32];
    __shared__ float cre[8][32], cim[8][32];
    __shared__ float dt_sh;
    if (threadIdx.x < 32){
        int n = threadIdx.x;
        float dt = expf(log_dt[h]);
        wre[n] = -expf(ivw[h*32+n]) * dt;
        wim[n] = wimag[h*32+n] * dt;
        bre[n] = B_ri[(h*32+n)*2+0];
        bim[n] = B_ri[(h*32+n)*2+1];
        ppre[n] = P_ri[(h*32+n)*2+0];
        ppim[n] = P_ri[(h*32+n)*2+1];
        if (n == 0) dt_sh = dt;
    }
    {
        int i = threadIdx.x;
        int cc = i >> 5, n = i & 31;
        size_t base = (((size_t)(c0+cc)*256 + h)*32 + n)*2;
        cre[cc][n] = C_ri[base+0];
        cim[cc][n] = C_ri[base+1];
    }
    __syncthreads();
    if (l >= LF) return;

    float4 zt = ZT[l];
    const float zx = zt.x, zy = zt.y;
    float r0x[9], r0y[9], r1x[9], r1y[9];
    #pragma unroll
    for (int j=0;j<9;++j){ r0x[j]=0.f; r0y[j]=0.f; r1x[j]=0.f; r1y[j]=0.f; }

    #pragma unroll 1
    for (int n=0; n<32; ++n){
        float wr = wre[n], wi = wim[n];
        float dx = zx - wr;
        float dy = zy - wi;
        float ey = zy + wi;
        float ip = 1.0f/(dx*dx + dy*dy);
        float im = 1.0f/(dx*dx + ey*ey);
        float cpx = dx*ip, cpy = -dy*ip;
        float cmx = dx*im, cmy = -ey*im;
        float br = bre[n], bi = bim[n];
        float t0x = br*cpx - bi*cpy, t0y = br*cpy + bi*cpx;
        float t1x = br*cmx + bi*cmy, t1y = br*cmy - bi*cmx;
        float pr = ppre[n], pi = ppim[n];
        float t2x = pr*cpx - pi*cpy, t2y = pr*cpy + pi*cpx;
        float t3x = pr*cmx + pi*cmy, t3y = pr*cmy - pi*cmx;
        float u0 = t0x+t1x, v0 = t1y-t0y, s0 = t0y+t1y, q0 = t0x-t1x;
        float u1 = t2x+t3x, v1 = t3y-t2y, s1 = t2y+t3y, q1 = t2x-t3x;
        #pragma unroll
        for (int j=0;j<8;++j){
            float a = cre[j][n], b = cim[j][n];
            r0x[j] = fmaf(a,u0, fmaf(b,v0, r0x[j]));
            r0y[j] = fmaf(a,s0, fmaf(b,q0, r0y[j]));
            r1x[j] = fmaf(a,u1, fmaf(b,v1, r1x[j]));
            r1y[j] = fmaf(a,s1, fmaf(b,q1, r1y[j]));
        }
        r0x[8] = fmaf(pr,u0, fmaf(-pi,v0, r0x[8]));
        r0y[8] = fmaf(pr,s0, fmaf(-pi,q0, r0y[8]));
        r1x[8] = fmaf(pr,u1, fmaf(-pi,v1, r1x[8]));
        r1y[8] = fmaf(pr,s1, fmaf(-pi,q1, r1y[8]));
    }

    float dt = dt_sh;
    #pragma unroll
    for (int j=0;j<9;++j){ r0x[j]*=dt; r0y[j]*=dt; r1x[j]*=dt; r1y[j]*=dt; }
    float drr = 1.0f + r1x[8], dii = r1y[8];
    float idn = 1.0f/(drr*drr + dii*dii);
    float gx = (r0x[8]*drr + r0y[8]*dii)*idn;
    float gy = (r0y[8]*drr - r0x[8]*dii)*idn;
    float tfx = zt.z, tfy = zt.w;
    #pragma unroll
    for (int j=0;j<8;++j){
        float kr = r0x[j] - (gx*r1x[j] - gy*r1y[j]);
        float ki = r0y[j] - (gx*r1y[j] + gy*r1x[j]);
        KF[((size_t)((c0+j)*256+h))*1026 + l] = make_float2(kr*tfx - ki*tfy, kr*tfy + ki*tfx);
    }
}

// ---------------- radix-8 butterfly on registers (post-twiddle) ----------------
template<bool INV>
__device__ __forceinline__ void bfly8(float2 v[8]){
    float2 e0,e1,e2,e3,o0,o1,o2,o3;
    {   // DFT4 of v0,v2,v4,v6
        float t0x=v[0].x+v[4].x, t0y=v[0].y+v[4].y;
        float t1x=v[0].x-v[4].x, t1y=v[0].y-v[4].y;
        float t2x=v[2].x+v[6].x, t2y=v[2].y+v[6].y;
        float t3x=v[2].x-v[6].x, t3y=v[2].y-v[6].y;
        e0 = make_float2(t0x+t2x, t0y+t2y);
        e2 = make_float2(t0x-t2x, t0y-t2y);
        if (!INV){ e1 = make_float2(t1x+t3y, t1y-t3x); e3 = make_float2(t1x-t3y, t1y+t3x); }
        else     { e1 = make_float2(t1x-t3y, t1y+t3x); e3 = make_float2(t1x+t3y, t1y-t3x); }
    }
    {   // DFT4 of v1,v3,v5,v7
        float t0x=v[1].x+v[5].x, t0y=v[1].y+v[5].y;
        float t1x=v[1].x-v[5].x, t1y=v[1].y-v[5].y;
        float t2x=v[3].x+v[7].x, t2y=v[3].y+v[7].y;
        float t3x=v[3].x-v[7].x, t3y=v[3].y-v[7].y;
        o0 = make_float2(t0x+t2x, t0y+t2y);
        o2 = make_float2(t0x-t2x, t0y-t2y);
        if (!INV){ o1 = make_float2(t1x+t3y, t1y-t3x); o3 = make_float2(t1x-t3y, t1y+t3x); }
        else     { o1 = make_float2(t1x-t3y, t1y+t3x); o3 = make_float2(t1x+t3y, t1y-t3x); }
    }
    const float RC = 0.70710678118654752f;
    float2 w1o1, w2o2, w3o3;
    if (!INV){
        w1o1 = make_float2(RC*(o1.x+o1.y), RC*(o1.y-o1.x));    // (1-i)/sqrt2
        w2o2 = make_float2(o2.y, -o2.x);                       // -i
        w3o3 = make_float2(RC*(o3.y-o3.x), RC*(-o3.x-o3.y));   // -(1+i)/sqrt2
    } else {
        w1o1 = make_float2(RC*(o1.x-o1.y), RC*(o1.y+o1.x));    // (1+i)/sqrt2
        w2o2 = make_float2(-o2.y, o2.x);                       // i
        w3o3 = make_float2(RC*(-o3.x-o3.y), RC*(o3.x-o3.y));   // (-1+i)/sqrt2
    }
    v[0] = make_float2(e0.x+o0.x,   e0.y+o0.y);
    v[1] = make_float2(e1.x+w1o1.x, e1.y+w1o1.y);
    v[2] = make_float2(e2.x+w2o2.x, e2.y+w2o2.y);
    v[3] = make_float2(e3.x+w3o3.x, e3.y+w3o3.y);
    v[4] = make_float2(e0.x-o0.x,   e0.y-o0.y);
    v[5] = make_float2(e1.x-w1o1.x, e1.y-w1o1.y);
    v[6] = make_float2(e2.x-w2o2.x, e2.y-w2o2.y);
    v[7] = make_float2(e3.x-w3o3.x, e3.y-w3o3.y);
}

// ---------------- Stockham stages (T=256, N=2048 fixed) ----------------
// Stage 1 (NS=1) is register-fed (s1_reg8): no twiddles, no entry barrier
// (caller guarantees the destination buffer passed a sync since last read).
template<bool INV>
__device__ __forceinline__ void s1_reg8(float2 v[8], float2* __restrict__ out){
    bfly8<INV>(v);
    int d = (int)threadIdx.x << 3;
    #pragma unroll
    for (int q=0;q<8;++q) out[pidx(d+q)] = v[q];
}

template<bool INV, int NS>
__device__ __forceinline__ void r8stage(const float2* __restrict__ in, float2* __restrict__ out){
    __syncthreads();
    int j = (int)threadIdx.x;
    int jm = j & (NS-1);
    float2 v[8];
    #pragma unroll
    for (int m=0;m<8;++m) v[m] = in[pidx(j + m*256)];
    {   // twiddle m*st/4096 revolutions; st = jm*4096/(NS*8); all exact dyadic
        const float SC = (float)(4096/(NS*8)) * (1.0f/4096.0f);
        float rb = (float)jm * SC;
        #pragma unroll
        for (int m=1;m<8;++m){
            float2 w = twid((float)m * rb);
            if (INV) w.y = -w.y;
            v[m] = cmulf(v[m], w);
        }
    }
    bfly8<INV>(v);
    int d = ((j - jm) << 3) + jm;
    #pragma unroll
    for (int q=0;q<8;++q) out[pidx(d + q*NS)] = v[q];
}

template<bool INV, int NS>   // NS=512, radix-4 final stage, 2 iterations
__device__ __forceinline__ void r4stage(const float2* __restrict__ in, float2* __restrict__ out){
    __syncthreads();
    #pragma unroll
    for (int it=0; it<2; ++it){
        int j = (int)threadIdx.x + it*256;
        int jm = j & (NS-1);
        float2 v0 = in[pidx(j)];
        float2 v1 = in[pidx(j +  512)];
        float2 v2 = in[pidx(j + 1024)];
        float2 v3 = in[pidx(j + 1536)];
        const float SC = (float)(4096/(NS*4)) * (1.0f/4096.0f);
        float rb = (float)jm * SC;
        float2 w1 = twid(rb), w2 = twid(2.0f*rb), w3 = twid(3.0f*rb);
        if (INV){ w1.y=-w1.y; w2.y=-w2.y; w3.y=-w3.y; }
        v1 = cmulf(v1,w1); v2 = cmulf(v2,w2); v3 = cmulf(v3,w3);
        float t0x=v0.x+v2.x, t0y=v0.y+v2.y;
        float t1x=v0.x-v2.x, t1y=v0.y-v2.y;
        float t2x=v1.x+v3.x, t2y=v1.y+v3.y;
        float t3x=v1.x-v3.x, t3y=v1.y-v3.y;
        float2 x0 = make_float2(t0x+t2x, t0y+t2y);
        float2 x2 = make_float2(t0x-t2x, t0y-t2y);
        float2 x1, x3;
        if (!INV){ x1 = make_float2(t1x+t3y, t1y-t3x); x3 = make_float2(t1x-t3y, t1y+t3x); }
        else     { x1 = make_float2(t1x-t3y, t1y+t3x); x3 = make_float2(t1x+t3y, t1y-t3x); }
        int d = ((j - jm) << 2) + jm;
        out[pidx(d)] = x0; out[pidx(d+NS)] = x1; out[pidx(d+2*NS)] = x2; out[pidx(d+3*NS)] = x3;
    }
}

// fft2048 from register inputs v (thread t owns slots t+m*256).
// s1 regs->A (no barrier: A passed a sync since its last read), A->B, B->A,
// A->B; ends in B; final sync included. v is clobbered.
template<bool INV>
__device__ __forceinline__ void fftR(float2 v[8], float2* __restrict__ A, float2* __restrict__ B){
    s1_reg8<INV>(v, A);
    r8stage<INV,8  >(A,B);
    r8stage<INV,64 >(B,A);
    r4stage<INV,512>(A,B);
    __syncthreads();
}

// ---------------- kernel C2: pd rows -> packed even/odd 4096-bin spectra ---------
__global__ __launch_bounds__(256) void kernC2(const float* __restrict__ pd,
                                              float2* __restrict__ PDE, float2* __restrict__ PDO){
    __shared__ float2 A[2176], Bb[2176];
    const int t = threadIdx.x;
    const int h = blockIdx.x;
    const float* p0 = pd + (size_t)h * 2048;
    const float* p1 = pd + (size_t)(256 + h) * 2048;
    float2 z[8], v[8];
    #pragma unroll
    for (int m=0;m<8;++m){
        int j = t + m*256;
        z[m] = make_float2(p0[j], p1[j]);
        v[m] = z[m];
    }
    fftR<false>(v, A, Bb);                    // ends in Bb
    float2* oe = PDE + (size_t)h * 2048;
    #pragma unroll
    for (int m=0;m<8;++m){ int j = t + m*256; oe[j] = Bb[pidx(j)]; }
    #pragma unroll
    for (int m=0;m<8;++m){
        int j = t + m*256;
        v[m] = cmulf(twid((float)j * (1.0f/4096.0f)), z[m]);   // * e^{-2pi i j/4096}
    }
    fftR<false>(v, A, Bb);                    // s2 entry sync guards Bb overwrite
    float2* oo = PDO + (size_t)h * 2048;
    #pragma unroll
    for (int m=0;m<8;++m){ int j = t + m*256; oo[j] = Bb[pidx(j)]; }
}

// ---------------- fused kernel F v6 ----------------
// Round-3 structure (pde_s+pdo_s staged, 67.6KB LDS, 2 blk/CU, grid y=2,
// pairing) kept: it is the verified-best plumbing (301us). Round-6 attacks the
// measured ~2700-cycle-per-stage stall (85% idle) inside the FFT engine:
//  1) twiddles via v_sin/v_cos (revolutions) - deletes the per-stage GLOBAL
//     twiddle gather (64 cache lines/instr at NS=64) and the 32KB TW table's
//     L1 pollution entirely.
//  2) register-fed stage 1 (fftR): pre-FFT passes (load*pde, pack, modulate,
//     product) feed the first butterfly from regs: -1 barrier, -8W -8R LDS
//     per FFT. Hazards: every buffer write is behind a stage-entry/final sync
//     relative to its last readers (see fftR contract).
// No launch_bounds: rounds 1/2/4 proved (256,k>=3) force-caps VGPR=256/k and
// spills (~1GB scratch traffic). Natural allocation ~128 (r3/r5) is clean.
__global__ void kernF(const float2* __restrict__ KFb,
                      const float2* __restrict__ PDE,
                      const float2* __restrict__ PDO,
                      const float* __restrict__ DCT,
                      float* __restrict__ out){
    __shared__ float2 A[2176], Bb[2176];
    __shared__ float2 pde_s[2048], pdo_s[2048];
    const int t = threadIdx.x;
    const int h = blockIdx.x;
    const int cq = blockIdx.y;                 // 0..1, 16 channels (8 pairs) each
    {
        const float2* pe = PDE + (size_t)h * 2048;
        const float2* po = PDO + (size_t)h * 2048;
        #pragma unroll
        for (int m=0;m<8;++m){
            int j = t + m*256;
            pde_s[j] = pe[j];
            pdo_s[j] = po[j];
        }
    }
    float accr[8], acci[8];
    #pragma unroll
    for (int m=0;m<8;++m){ accr[m]=0.f; acci[m]=0.f; }
    __syncthreads();                            // pde_s/pdo_s visible to all

    #pragma unroll 1
    for (int pp=0; pp<8; ++pp){
        const int ca = cq*16 + pp*2;
        const float2* ra = KFb + (size_t)(ca*256+h)*1026;
        const float2* rb = KFb + (size_t)((ca+1)*256+h)*1026;

        // prefetch dct for both channels (consumed after FFTs; hides latency)
        float dcva[8], dcvb[8];
        {
            const float* dcta = DCT + (size_t)(h*32 + ca) * 2048;
            const float* dctb = dcta + 2048;
            #pragma unroll
            for (int m=0;m<8;++m){
                int j = t + m*256;
                dcva[m] = dcta[j] * (1.0f/4096.0f);
                dcvb[m] = dctb[j] * (1.0f/4096.0f);
            }
        }
        float2 v[8];

        // ---- Phase E, channel a: ifft(pde * Herm(kf_a)); accumulate ----
        #pragma unroll
        for (int m=0;m<8;++m){
            int j = t + m*256;
            float2 u;
            if (j <= 1024) u = ra[j];
            else { float2 w = ra[2048-j]; u = make_float2(w.x, -w.y); }  // Hermitian
            v[m] = cmulf(pde_s[j], u);
        }
        fftR<true>(v, A, Bb);                  // ends in Bb
        #pragma unroll
        for (int m=0;m<8;++m){
            int j = t + m*256;
            float2 xe = Bb[pidx(j)];
            accr[m] = fmaf(xe.x, dcva[m], accr[m]);
            acci[m] = fmaf(xe.y, dcva[m], acci[m]);
        }
        // ---- Phase E, channel b ----
        #pragma unroll
        for (int m=0;m<8;++m){
            int j = t + m*256;
            float2 u;
            if (j <= 1024) u = rb[j];
            else { float2 w = rb[2048-j]; u = make_float2(w.x, -w.y); }
            v[m] = cmulf(pde_s[j], u);
        }
        fftR<true>(v, A, Bb);
        #pragma unroll
        for (int m=0;m<8;++m){
            int j = t + m*256;
            float2 xe = Bb[pidx(j)];
            accr[m] = fmaf(xe.x, dcvb[m], accr[m]);
            acci[m] = fmaf(xe.y, dcvb[m], acci[m]);
        }

        // ---- Phase O (paired): ifft(Herm_a + i*Herm_b) = 2048*(k_a + i*k_b) ----
        #pragma unroll
        for (int m=0;m<8;++m){
            int j = t + m*256;
            float2 va, vb;
            if (j <= 1024){ va = ra[j]; vb = rb[j]; }
            else {
                float2 u = ra[2048-j]; va = make_float2(u.x, -u.y);
                float2 w = rb[2048-j]; vb = make_float2(w.x, -w.y);
            }
            v[m] = make_float2(va.x - vb.y, va.y + vb.x);
        }
        fftR<true>(v, A, Bb);                  // packed k in Bb
        // modulate own slots (post final sync), feed Z-fft from regs
        #pragma unroll
        for (int m=0;m<8;++m){
            int j = t + m*256;
            float2 kk = Bb[pidx(j)];
            kk.x *= (1.0f/2048.0f); kk.y *= (1.0f/2048.0f);
            v[m] = cmulf(kk, twid((float)j * (1.0f/4096.0f)));   // * e^{-2pi i j/4096}
        }
        fftR<false>(v, A, Bb);                 // Z = K2odd_a + i*K2odd_b in Bb

        // unpack + products (cross reads of Bb, behind fftR's final sync)
        float2 pa[8], sb[8];
        #pragma unroll
        for (int m=0;m<8;++m){
            int j  = t + m*256;
            int jm2 = 2047 - j;
            float2 z  = Bb[pidx(j)];
            float2 zm = Bb[pidx(jm2)];
            float2 Ka = make_float2(0.5f*(z.x + zm.x), 0.5f*(z.y - zm.y));
            float2 Kb = make_float2(0.5f*(z.y + zm.y), 0.5f*(zm.x - z.x));
            float2 pov = pdo_s[j];
            pa[m] = cmulf(pov, Ka);
            sb[m] = cmulf(pov, Kb);
        }
        // ifft channel a (s1 writes A: safe; s2 entry sync guards Bb overwrite)
        fftR<true>(pa, A, Bb);
        #pragma unroll
        for (int m=0;m<8;++m){
            int j = t + m*256;
            float2 w = twid((float)j * (1.0f/4096.0f));
            float2 ee = make_float2(w.x, -w.y);      // e^{+2pi i j/4096}
            float2 rot = cmulf(ee, Bb[pidx(j)]);
            accr[m] = fmaf(rot.x, dcva[m], accr[m]);
            acci[m] = fmaf(rot.y, dcva[m], acci[m]);
        }
        // ifft channel b from held regs
        fftR<true>(sb, A, Bb);
        #pragma unroll
        for (int m=0;m<8;++m){
            int j = t + m*256;
            float2 w = twid((float)j * (1.0f/4096.0f));
            float2 ee = make_float2(w.x, -w.y);
            float2 rot = cmulf(ee, Bb[pidx(j)]);
            accr[m] = fmaf(rot.x, dcvb[m], accr[m]);
            acci[m] = fmaf(rot.y, dcvb[m], acci[m]);
        }
    }
    #pragma unroll
    for (int m=0;m<8;++m){
        int j = t + m*256;
        atomicAdd(&out[((size_t)h)*2048 + j],       accr[m]);   // batch 0 (Re)
        atomicAdd(&out[((size_t)(256+h))*2048 + j], acci[m]);   // batch 1 (Im)
    }
}

extern "C" void kernel_launch(void* const* d_in, const int* in_sizes, int n_in,
                              void* d_out, int out_size, void* d_ws, size_t ws_size,
                              hipStream_t stream) {
    const float* log_dt = (const float*)d_in[0];
    const float* B_ri   = (const float*)d_in[1];
    const float* P_ri   = (const float*)d_in[2];
    const float* C_ri   = (const float*)d_in[3];
    const float* ivw    = (const float*)d_in[4];
    const float* wimag  = (const float*)d_in[5];
    const float* dC     = (const float*)d_in[6];
    const float* pd     = (const float*)d_in[7];

    char* ws = (char*)d_ws;
    float4* ZT  = (float4*)(ws + OFF_ZT);
    float2* KF  = (float2*)(ws + OFF_KF);
    float2* PDE = (float2*)(ws + OFF_PDF);
    float2* PDO = (float2*)(ws + OFF_PDF + 256*2048*sizeof(float2));
    float*  DCT = (float*) (ws + OFF_DCT);
    float* out = (float*)d_out;

    hipMemsetAsync(out, 0, (size_t)out_size * sizeof(float), stream);
    initk<<<5, 256, 0, stream>>>(ZT);
    transpose_dC<<<dim3(256,64), dim3(32,8), 0, stream>>>(dC, DCT);
    cauchy_k<<<dim3(5,256,4), 256, 0, stream>>>(log_dt, B_ri, P_ri, C_ri, ivw, wimag, ZT, KF);
    kernC2<<<256, 256, 0, stream>>>(pd, PDE, PDO);
    kernF<<<dim3(256,2), 256, 0, stream>>>((const float2*)KF, PDE, PDO, DCT, out);
}

// Round 7
// 439.836 us; speedup vs baseline: 2.1951x; 2.1951x over previous
//
#include <hip/hip_runtime.h>
#include <math.h>

// Problem constants (reference: H=256, N=32, S=256, R=1, CCH=32, L=2048, B=2)
#define LF   1025     // L/2+1

// ---- workspace layout (bytes) ----
// (TW region @0 retired - twiddles now computed via v_sin/v_cos in-register)
#define OFF_ZT   65536
#define OFF_KF   131072
#define OFF_PDF  67371008
#define OFF_DCT  84148224

__device__ __forceinline__ float2 cmulf(float2 a, float2 b){
    return make_float2(a.x*b.x - a.y*b.y, a.x*b.y + a.y*b.x);
}
// LDS padding: 1 extra float2 per 16 -> breaks power-of-2 bank aliasing of the
// Stockham scatter.
__device__ __forceinline__ int pidx(int i){ return i + (i >> 4); }

// e^{-2 pi i r}, 0 <= r < 1 (exact dyadic). v_sin/v_cos take REVOLUTIONS on
// gfx9xx -> no table, no gather, no range reduction needed.
__device__ __forceinline__ float2 twid(float r){
    float s, c;
    asm("v_sin_f32 %0, %1" : "=v"(s) : "v"(r));
    asm("v_cos_f32 %0, %1" : "=v"(c) : "v"(r));
    return make_float2(c, -s);
}

// ---------------- init: bilinear nodes (fp64 once) ----------------
__global__ void initk(float4* __restrict__ ZT){
    int i = blockIdx.x*256 + threadIdx.x;
    if (i < LF){
        double th = (-2.0*M_PI) * (double)i / 2048.0;
        double cr = cos(th), ci = sin(th);
        double ar = 1.0 + cr, ai = ci;              // 1+w
        double den = ar*ar + ai*ai;
        double nr = 1.0 - cr, ni = -ci;             // 1-w
        double zr = 2.0*(nr*ar + ni*ai)/den;        // z = 2(1-w)/(1+w)
        double zi = 2.0*(ni*ar - nr*ai)/den;
        ZT[i] = make_float4((float)zr, (float)zi, (float)(2.0*ar/den), (float)(-2.0*ai/den));
    }
}

// ---------------- dC (l, h, c) -> DCT (h*32+c, l) ----------------
__global__ void transpose_dC(const float* __restrict__ dC, float* __restrict__ DCT){
    __shared__ float tile[32][33];
    int hc0 = blockIdx.x*32;
    int l0  = blockIdx.y*32;
    int tx = threadIdx.x;
    for (int i = threadIdx.y; i < 32; i += 8)
        tile[i][tx] = dC[(size_t)(l0+i)*8192 + hc0 + tx];
    __syncthreads();
    for (int i = threadIdx.y; i < 32; i += 8)
        DCT[(size_t)(hc0+i)*2048 + l0 + tx] = tile[tx][i];
}

// ---------------- Cauchy + Woodbury -> k_f ---------------- (unchanged, passes)
__global__ __launch_bounds__(256) void cauchy_k(
                         const float* __restrict__ log_dt, const float* __restrict__ B_ri,
                         const float* __restrict__ P_ri, const float* __restrict__ C_ri,
                         const float* __restrict__ ivw, const float* __restrict__ wimag,
                         const float4* __restrict__ ZT, float2* __restrict__ KF)
{
    const int h  = blockIdx.y;
    const int c0 = blockIdx.z * 8;
    const int l  = blockIdx.x*256 + (int)threadIdx.x;
    __shared__ float wre[32], wim[32], bre[32], bim[32], ppre[32], ppim[32];
    __shared__ float cre[8][32], cim[8][32];
    __shared__ float dt_sh;
    if (threadIdx.x < 32){
        int n = threadIdx.x;
        float dt = expf(log_dt[h]);
        wre[n] = -expf(ivw[h*32+n]) * dt;
        wim[n] = wimag[h*32+n] * dt;
        bre[n] = B_ri[(h*32+n)*2+0];
        bim[n] = B_ri[(h*32+n)*2+1];
        ppre[n] = P_ri[(h*32+n)*2+0];
        ppim[n] = P_ri[(h*32+n)*2+1];
        if (n == 0) dt_sh = dt;
    }
    {
        int i = threadIdx.x;
        int cc = i >> 5, n = i & 31;
        size_t base = (((size_t)(c0+cc)*256 + h)*32 + n)*2;
        cre[cc][n] = C_ri[base+0];
        cim[cc][n] = C_ri[base+1];
    }
    __syncthreads();
    if (l >= LF) return;

    float4 zt = ZT[l];
    const float zx = zt.x, zy = zt.y;
    float r0x[9], r0y[9], r1x[9], r1y[9];
    #pragma unroll
    for (int j=0;j<9;++j){ r0x[j]=0.f; r0y[j]=0.f; r1x[j]=0.f; r1y[j]=0.f; }

    #pragma unroll 1
    for (int n=0; n<32; ++n){
        float wr = wre[n], wi = wim[n];
        float dx = zx - wr;
        float dy = zy - wi;
        float ey = zy + wi;
        float ip = 1.0f/(dx*dx + dy*dy);
        float im = 1.0f/(dx*dx + ey*ey);
        float cpx = dx*ip, cpy = -dy*ip;
        float cmx = dx*im, cmy = -ey*im;
        float br = bre[n], bi = bim[n];
        float t0x = br*cpx - bi*cpy, t0y = br*cpy + bi*cpx;
        float t1x = br*cmx + bi*cmy, t1y = br*cmy - bi*cmx;
        float pr = ppre[n], pi = ppim[n];
        float t2x = pr*cpx - pi*cpy, t2y = pr*cpy + pi*cpx;
        float t3x = pr*cmx + pi*cmy, t3y = pr*cmy - pi*cmx;
        float u0 = t0x+t1x, v0 = t1y-t0y, s0 = t0y+t1y, q0 = t0x-t1x;
        float u1 = t2x+t3x, v1 = t3y-t2y, s1 = t2y+t3y, q1 = t2x-t3x;
        #pragma unroll
        for (int j=0;j<8;++j){
            float a = cre[j][n], b = cim[j][n];
            r0x[j] = fmaf(a,u0, fmaf(b,v0, r0x[j]));
            r0y[j] = fmaf(a,s0, fmaf(b,q0, r0y[j]));
            r1x[j] = fmaf(a,u1, fmaf(b,v1, r1x[j]));
            r1y[j] = fmaf(a,s1, fmaf(b,q1, r1y[j]));
        }
        r0x[8] = fmaf(pr,u0, fmaf(-pi,v0, r0x[8]));
        r0y[8] = fmaf(pr,s0, fmaf(-pi,q0, r0y[8]));
        r1x[8] = fmaf(pr,u1, fmaf(-pi,v1, r1x[8]));
        r1y[8] = fmaf(pr,s1, fmaf(-pi,q1, r1y[8]));
    }

    float dt = dt_sh;
    #pragma unroll
    for (int j=0;j<9;++j){ r0x[j]*=dt; r0y[j]*=dt; r1x[j]*=dt; r1y[j]*=dt; }
    float drr = 1.0f + r1x[8], dii = r1y[8];
    float idn = 1.0f/(drr*drr + dii*dii);
    float gx = (r0x[8]*drr + r0y[8]*dii)*idn;
    float gy = (r0y[8]*drr - r0x[8]*dii)*idn;
    float tfx = zt.z, tfy = zt.w;
    #pragma unroll
    for (int j=0;j<8;++j){
        float kr = r0x[j] - (gx*r1x[j] - gy*r1y[j]);
        float ki = r0y[j] - (gx*r1y[j] + gy*r1x[j]);
        KF[((size_t)((c0+j)*256+h))*1026 + l] = make_float2(kr*tfx - ki*tfy, kr*tfy + ki*tfx);
    }
}

// ---------------- radix-8 butterfly on registers (post-twiddle) ----------------
template<bool INV>
__device__ __forceinline__ void bfly8(float2 v[8]){
    float2 e0,e1,e2,e3,o0,o1,o2,o3;
    {   // DFT4 of v0,v2,v4,v6
        float t0x=v[0].x+v[4].x, t0y=v[0].y+v[4].y;
        float t1x=v[0].x-v[4].x, t1y=v[0].y-v[4].y;
        float t2x=v[2].x+v[6].x, t2y=v[2].y+v[6].y;
        float t3x=v[2].x-v[6].x, t3y=v[2].y-v[6].y;
        e0 = make_float2(t0x+t2x, t0y+t2y);
        e2 = make_float2(t0x-t2x, t0y-t2y);
        if (!INV){ e1 = make_float2(t1x+t3y, t1y-t3x); e3 = make_float2(t1x-t3y, t1y+t3x); }
        else     { e1 = make_float2(t1x-t3y, t1y+t3x); e3 = make_float2(t1x+t3y, t1y-t3x); }
    }
    {   // DFT4 of v1,v3,v5,v7
        float t0x=v[1].x+v[5].x, t0y=v[1].y+v[5].y;
        float t1x=v[1].x-v[5].x, t1y=v[1].y-v[5].y;
        float t2x=v[3].x+v[7].x, t2y=v[3].y+v[7].y;
        float t3x=v[3].x-v[7].x, t3y=v[3].y-v[7].y;
        o0 = make_float2(t0x+t2x, t0y+t2y);
        o2 = make_float2(t0x-t2x, t0y-t2y);
        if (!INV){ o1 = make_float2(t1x+t3y, t1y-t3x); o3 = make_float2(t1x-t3y, t1y+t3x); }
        else     { o1 = make_float2(t1x-t3y, t1y+t3x); o3 = make_float2(t1x+t3y, t1y-t3x); }
    }
    const float RC = 0.70710678118654752f;
    float2 w1o1, w2o2, w3o3;
    if (!INV){
        w1o1 = make_float2(RC*(o1.x+o1.y), RC*(o1.y-o1.x));    // (1-i)/sqrt2
        w2o2 = make_float2(o2.y, -o2.x);                       // -i
        w3o3 = make_float2(RC*(o3.y-o3.x), RC*(-o3.x-o3.y));   // -(1+i)/sqrt2
    } else {
        w1o1 = make_float2(RC*(o1.x-o1.y), RC*(o1.y+o1.x));    // (1+i)/sqrt2
        w2o2 = make_float2(-o2.y, o2.x);                       // i
        w3o3 = make_float2(RC*(-o3.x-o3.y), RC*(o3.x-o3.y));   // (-1+i)/sqrt2
    }
    v[0] = make_float2(e0.x+o0.x,   e0.y+o0.y);
    v[1] = make_float2(e1.x+w1o1.x, e1.y+w1o1.y);
    v[2] = make_float2(e2.x+w2o2.x, e2.y+w2o2.y);
    v[3] = make_float2(e3.x+w3o3.x, e3.y+w3o3.y);
    v[4] = make_float2(e0.x-o0.x,   e0.y-o0.y);
    v[5] = make_float2(e1.x-w1o1.x, e1.y-w1o1.y);
    v[6] = make_float2(e2.x-w2o2.x, e2.y-w2o2.y);
    v[7] = make_float2(e3.x-w3o3.x, e3.y-w3o3.y);
}

// ---------------- Stockham stages (T=256, N=2048 fixed) ----------------
// Stage 1 (NS=1) is register-fed (s1_reg8): no twiddles, no entry barrier
// (caller guarantees the destination buffer passed a sync since last read).
template<bool INV>
__device__ __forceinline__ void s1_reg8(float2 v[8], float2* __restrict__ out){
    bfly8<INV>(v);
    int d = (int)threadIdx.x << 3;
    #pragma unroll
    for (int q=0;q<8;++q) out[pidx(d+q)] = v[q];
}

template<bool INV, int NS>
__device__ __forceinline__ void r8stage(const float2* __restrict__ in, float2* __restrict__ out){
    __syncthreads();
    int j = (int)threadIdx.x;
    int jm = j & (NS-1);
    float2 v[8];
    #pragma unroll
    for (int m=0;m<8;++m) v[m] = in[pidx(j + m*256)];
    {   // twiddle m*st/4096 revolutions; st = jm*4096/(NS*8); all exact dyadic
        const float SC = (float)(4096/(NS*8)) * (1.0f/4096.0f);
        float rb = (float)jm * SC;
        #pragma unroll
        for (int m=1;m<8;++m){
            float2 w = twid((float)m * rb);
            if (INV) w.y = -w.y;
            v[m] = cmulf(v[m], w);
        }
    }
    bfly8<INV>(v);
    int d = ((j - jm) << 3) + jm;
    #pragma unroll
    for (int q=0;q<8;++q) out[pidx(d + q*NS)] = v[q];
}

template<bool INV, int NS>   // NS=512, radix-4 final stage, 2 iterations
__device__ __forceinline__ void r4stage(const float2* __restrict__ in, float2* __restrict__ out){
    __syncthreads();
    #pragma unroll
    for (int it=0; it<2; ++it){
        int j = (int)threadIdx.x + it*256;
        int jm = j & (NS-1);
        float2 v0 = in[pidx(j)];
        float2 v1 = in[pidx(j +  512)];
        float2 v2 = in[pidx(j + 1024)];
        float2 v3 = in[pidx(j + 1536)];
        const float SC = (float)(4096/(NS*4)) * (1.0f/4096.0f);
        float rb = (float)jm * SC;
        float2 w1 = twid(rb), w2 = twid(2.0f*rb), w3 = twid(3.0f*rb);
        if (INV){ w1.y=-w1.y; w2.y=-w2.y; w3.y=-w3.y; }
        v1 = cmulf(v1,w1); v2 = cmulf(v2,w2); v3 = cmulf(v3,w3);
        float t0x=v0.x+v2.x, t0y=v0.y+v2.y;
        float t1x=v0.x-v2.x, t1y=v0.y-v2.y;
        float t2x=v1.x+v3.x, t2y=v1.y+v3.y;
        float t3x=v1.x-v3.x, t3y=v1.y-v3.y;
        float2 x0 = make_float2(t0x+t2x, t0y+t2y);
        float2 x2 = make_float2(t0x-t2x, t0y-t2y);
        float2 x1, x3;
        if (!INV){ x1 = make_float2(t1x+t3y, t1y-t3x); x3 = make_float2(t1x-t3y, t1y+t3x); }
        else     { x1 = make_float2(t1x-t3y, t1y+t3x); x3 = make_float2(t1x+t3y, t1y-t3x); }
        int d = ((j - jm) << 2) + jm;
        out[pidx(d)] = x0; out[pidx(d+NS)] = x1; out[pidx(d+2*NS)] = x2; out[pidx(d+3*NS)] = x3;
    }
}

// fft2048 from register inputs v (thread t owns slots t+m*256).
// s1 regs->A (no barrier: A passed a sync since its last read), A->B, B->A,
// A->B; ends in B; final sync included. v is clobbered.
template<bool INV>
__device__ __forceinline__ void fftR(float2 v[8], float2* __restrict__ A, float2* __restrict__ B){
    s1_reg8<INV>(v, A);
    r8stage<INV,8  >(A,B);
    r8stage<INV,64 >(B,A);
    r4stage<INV,512>(A,B);
    __syncthreads();
}

// ---------------- kernel C2: pd rows -> packed even/odd 4096-bin spectra ---------
__global__ __launch_bounds__(256,2) void kernC2(const float* __restrict__ pd,
                                                float2* __restrict__ PDE, float2* __restrict__ PDO){
    __shared__ float2 A[2176], Bb[2176];
    const int t = threadIdx.x;
    const int h = blockIdx.x;
    const float* p0 = pd + (size_t)h * 2048;
    const float* p1 = pd + (size_t)(256 + h) * 2048;
    float2 z[8], v[8];
    #pragma unroll
    for (int m=0;m<8;++m){
        int j = t + m*256;
        z[m] = make_float2(p0[j], p1[j]);
        v[m] = z[m];
    }
    fftR<false>(v, A, Bb);                    // ends in Bb
    float2* oe = PDE + (size_t)h * 2048;
    #pragma unroll
    for (int m=0;m<8;++m){ int j = t + m*256; oe[j] = Bb[pidx(j)]; }
    #pragma unroll
    for (int m=0;m<8;++m){
        int j = t + m*256;
        v[m] = cmulf(twid((float)j * (1.0f/4096.0f)), z[m]);   // * e^{-2pi i j/4096}
    }
    fftR<false>(v, A, Bb);                    // s2 entry sync guards Bb overwrite
    float2* oo = PDO + (size_t)h * 2048;
    #pragma unroll
    for (int m=0;m<8;++m){ int j = t + m*256; oo[j] = Bb[pidx(j)]; }
}

// ---------------- fused kernel F v7 ----------------
// Round-7: round-6 body UNCHANGED, but __launch_bounds__(256,2) RESTORED.
// Toolchain law mapped over rounds 0-6 (VGPR_Count / spill):
//   none->64/spill, (256,4)->64/spill, (256,3)->84/spill, (256,2)->128/clean.
// Round-6's content changes are real (bank conflicts 1.13e7 -> 9.7e6 from the
// register-fed stage 1; TW table deleted) but were buried under ~1.3GB of
// scratch traffic from the 64-VGPR default cap. This round measures them
// cleanly:
//  1) twiddles via v_sin/v_cos (revolutions) - no per-stage global gather.
//  2) register-fed stage 1: -1 barrier, -8W -8R LDS per FFT.
//  3) round-3 plumbing: pde_s/pdo_s staged, 67.6KB LDS, grid y=2, pairing.
// Spill tripwire: FETCH>600MB or WRITE>250MB.
__global__ __launch_bounds__(256,2) void kernF(const float2* __restrict__ KFb,
                                               const float2* __restrict__ PDE,
                                               const float2* __restrict__ PDO,
                                               const float* __restrict__ DCT,
                                               float* __restrict__ out){
    __shared__ float2 A[2176], Bb[2176];
    __shared__ float2 pde_s[2048], pdo_s[2048];
    const int t = threadIdx.x;
    const int h = blockIdx.x;
    const int cq = blockIdx.y;                 // 0..1, 16 channels (8 pairs) each
    {
        const float2* pe = PDE + (size_t)h * 2048;
        const float2* po = PDO + (size_t)h * 2048;
        #pragma unroll
        for (int m=0;m<8;++m){
            int j = t + m*256;
            pde_s[j] = pe[j];
            pdo_s[j] = po[j];
        }
    }
    float accr[8], acci[8];
    #pragma unroll
    for (int m=0;m<8;++m){ accr[m]=0.f; acci[m]=0.f; }
    __syncthreads();                            // pde_s/pdo_s visible to all

    #pragma unroll 1
    for (int pp=0; pp<8; ++pp){
        const int ca = cq*16 + pp*2;
        const float2* ra = KFb + (size_t)(ca*256+h)*1026;
        const float2* rb = KFb + (size_t)((ca+1)*256+h)*1026;

        // prefetch dct for both channels (consumed after FFTs; hides latency)
        float dcva[8], dcvb[8];
        {
            const float* dcta = DCT + (size_t)(h*32 + ca) * 2048;
            const float* dctb = dcta + 2048;
            #pragma unroll
            for (int m=0;m<8;++m){
                int j = t + m*256;
                dcva[m] = dcta[j] * (1.0f/4096.0f);
                dcvb[m] = dctb[j] * (1.0f/4096.0f);
            }
        }
        float2 v[8];

        // ---- Phase E, channel a: ifft(pde * Herm(kf_a)); accumulate ----
        #pragma unroll
        for (int m=0;m<8;++m){
            int j = t + m*256;
            float2 u;
            if (j <= 1024) u = ra[j];
            else { float2 w = ra[2048-j]; u = make_float2(w.x, -w.y); }  // Hermitian
            v[m] = cmulf(pde_s[j], u);
        }
        fftR<true>(v, A, Bb);                  // ends in Bb
        #pragma unroll
        for (int m=0;m<8;++m){
            int j = t + m*256;
            float2 xe = Bb[pidx(j)];
            accr[m] = fmaf(xe.x, dcva[m], accr[m]);
            acci[m] = fmaf(xe.y, dcva[m], acci[m]);
        }
        // ---- Phase E, channel b ----
        #pragma unroll
        for (int m=0;m<8;++m){
            int j = t + m*256;
            float2 u;
            if (j <= 1024) u = rb[j];
            else { float2 w = rb[2048-j]; u = make_float2(w.x, -w.y); }
            v[m] = cmulf(pde_s[j], u);
        }
        fftR<true>(v, A, Bb);
        #pragma unroll
        for (int m=0;m<8;++m){
            int j = t + m*256;
            float2 xe = Bb[pidx(j)];
            accr[m] = fmaf(xe.x, dcvb[m], accr[m]);
            acci[m] = fmaf(xe.y, dcvb[m], acci[m]);
        }

        // ---- Phase O (paired): ifft(Herm_a + i*Herm_b) = 2048*(k_a + i*k_b) ----
        #pragma unroll
        for (int m=0;m<8;++m){
            int j = t + m*256;
            float2 va, vb;
            if (j <= 1024){ va = ra[j]; vb = rb[j]; }
            else {
                float2 u = ra[2048-j]; va = make_float2(u.x, -u.y);
                float2 w = rb[2048-j]; vb = make_float2(w.x, -w.y);
            }
            v[m] = make_float2(va.x - vb.y, va.y + vb.x);
        }
        fftR<true>(v, A, Bb);                  // packed k in Bb
        // modulate own slots (post final sync), feed Z-fft from regs
        #pragma unroll
        for (int m=0;m<8;++m){
            int j = t + m*256;
            float2 kk = Bb[pidx(j)];
            kk.x *= (1.0f/2048.0f); kk.y *= (1.0f/2048.0f);
            v[m] = cmulf(kk, twid((float)j * (1.0f/4096.0f)));   // * e^{-2pi i j/4096}
        }
        fftR<false>(v, A, Bb);                 // Z = K2odd_a + i*K2odd_b in Bb

        // unpack + products (cross reads of Bb, behind fftR's final sync)
        float2 pa[8], sb[8];
        #pragma unroll
        for (int m=0;m<8;++m){
            int j  = t + m*256;
            int jm2 = 2047 - j;
            float2 z  = Bb[pidx(j)];
            float2 zm = Bb[pidx(jm2)];
            float2 Ka = make_float2(0.5f*(z.x + zm.x), 0.5f*(z.y - zm.y));
            float2 Kb = make_float2(0.5f*(z.y + zm.y), 0.5f*(zm.x - z.x));
            float2 pov = pdo_s[j];
            pa[m] = cmulf(pov, Ka);
            sb[m] = cmulf(pov, Kb);
        }
        // ifft channel a (s1 writes A: safe; s2 entry sync guards Bb overwrite)
        fftR<true>(pa, A, Bb);
        #pragma unroll
        for (int m=0;m<8;++m){
            int j = t + m*256;
            float2 w = twid((float)j * (1.0f/4096.0f));
            float2 ee = make_float2(w.x, -w.y);      // e^{+2pi i j/4096}
            float2 rot = cmulf(ee, Bb[pidx(j)]);
            accr[m] = fmaf(rot.x, dcva[m], accr[m]);
            acci[m] = fmaf(rot.y, dcva[m], acci[m]);
        }
        // ifft channel b from held regs
        fftR<true>(sb, A, Bb);
        #pragma unroll
        for (int m=0;m<8;++m){
            int j = t + m*256;
            float2 w = twid((float)j * (1.0f/4096.0f));
            float2 ee = make_float2(w.x, -w.y);
            float2 rot = cmulf(ee, Bb[pidx(j)]);
            accr[m] = fmaf(rot.x, dcvb[m], accr[m]);
            acci[m] = fmaf(rot.y, dcvb[m], acci[m]);
        }
    }
    #pragma unroll
    for (int m=0;m<8;++m){
        int j = t + m*256;
        atomicAdd(&out[((size_t)h)*2048 + j],       accr[m]);   // batch 0 (Re)
        atomicAdd(&out[((size_t)(256+h))*2048 + j], acci[m]);   // batch 1 (Im)
    }
}

extern "C" void kernel_launch(void* const* d_in, const int* in_sizes, int n_in,
                              void* d_out, int out_size, void* d_ws, size_t ws_size,
                              hipStream_t stream) {
    const float* log_dt = (const float*)d_in[0];
    const float* B_ri   = (const float*)d_in[1];
    const float* P_ri   = (const float*)d_in[2];
    const float* C_ri   = (const float*)d_in[3];
    const float* ivw    = (const float*)d_in[4];
    const float* wimag  = (const float*)d_in[5];
    const float* dC     = (const float*)d_in[6];
    const float* pd     = (const float*)d_in[7];

    char* ws = (char*)d_ws;
    float4* ZT  = (float4*)(ws + OFF_ZT);
    float2* KF  = (float2*)(ws + OFF_KF);
    float2* PDE = (float2*)(ws + OFF_PDF);
    float2* PDO = (float2*)(ws + OFF_PDF + 256*2048*sizeof(float2));
    float*  DCT = (float*) (ws + OFF_DCT);
    float* out = (float*)d_out;

    hipMemsetAsync(out, 0, (size_t)out_size * sizeof(float), stream);
    initk<<<5, 256, 0, stream>>>(ZT);
    transpose_dC<<<dim3(256,64), dim3(32,8), 0, stream>>>(dC, DCT);
    cauchy_k<<<dim3(5,256,4), 256, 0, stream>>>(log_dt, B_ri, P_ri, C_ri, ivw, wimag, ZT, KF);
    kernC2<<<256, 256, 0, stream>>>(pd, PDE, PDO);
    kernF<<<dim3(256,2), 256, 0, stream>>>((const float2*)KF, PDE, PDO, DCT, out);
}

// Round 8
// 364.796 us; speedup vs baseline: 2.6466x; 1.2057x over previous
//
#include <hip/hip_runtime.h>
#include <math.h>

// Problem constants (reference: H=256, N=32, S=256, R=1, CCH=32, L=2048, B=2)
#define LF   1025     // L/2+1

// ---- workspace layout (bytes) ----
#define OFF_ZT   65536
#define OFF_KF   131072
#define OFF_PDF  67371008
#define OFF_DCT  84148224

__device__ __forceinline__ float2 cmulf(float2 a, float2 b){
    return make_float2(a.x*b.x - a.y*b.y, a.x*b.y + a.y*b.x);
}

// e^{-2 pi i r}, 0 <= r < 1 (exact dyadic). v_sin/v_cos take REVOLUTIONS on
// gfx9xx -> no table, no gather, no range reduction needed.
__device__ __forceinline__ float2 twid(float r){
    float s, c;
    asm("v_sin_f32 %0, %1" : "=v"(s) : "v"(r));
    asm("v_cos_f32 %0, %1" : "=v"(c) : "v"(r));
    return make_float2(c, -s);
}
// fast reciprocal (~1 ulp) - tolerance is 7.8e-3, plenty of margin
__device__ __forceinline__ float frcp(float x){
    float y; asm("v_rcp_f32 %0, %1" : "=v"(y) : "v"(x)); return y;
}
// own-wave LDS ordering fence: waits this wave's ds ops; asm volatile+memory
// is also a compiler reorder barrier for the surrounding ds_read/ds_write.
__device__ __forceinline__ void lds_fence(){
    asm volatile("s_waitcnt lgkmcnt(0)" ::: "memory");
}

// FFT buffers: 4 groups x 512, group stride 548 (8-bank offset between groups,
// 1096 words % 32 == 8) + intra-group pad every 16.
#define GS 548
__device__ __forceinline__ int gslot(int g, int s){ return g*GS + s + (s >> 4); }
// post-FFT: bin j lives at gslot(j&3, j>>2)  (X[4s+g] stored at group g, slot s)
__device__ __forceinline__ int binslot(int j){ return gslot(j & 3, j >> 2); }

// ---------------- init: bilinear nodes (fp64 once) ----------------
__global__ void initk(float4* __restrict__ ZT){
    int i = blockIdx.x*256 + threadIdx.x;
    if (i < LF){
        double th = (-2.0*M_PI) * (double)i / 2048.0;
        double cr = cos(th), ci = sin(th);
        double ar = 1.0 + cr, ai = ci;              // 1+w
        double den = ar*ar + ai*ai;
        double nr = 1.0 - cr, ni = -ci;             // 1-w
        double zr = 2.0*(nr*ar + ni*ai)/den;        // z = 2(1-w)/(1+w)
        double zi = 2.0*(ni*ar - nr*ai)/den;
        ZT[i] = make_float4((float)zr, (float)zi, (float)(2.0*ar/den), (float)(-2.0*ai/den));
    }
}

// ---------------- dC (l, h, c) -> DCT (h*32+c, l) ----------------
__global__ void transpose_dC(const float* __restrict__ dC, float* __restrict__ DCT){
    __shared__ float tile[32][33];
    int hc0 = blockIdx.x*32;
    int l0  = blockIdx.y*32;
    int tx = threadIdx.x;
    for (int i = threadIdx.y; i < 32; i += 8)
        tile[i][tx] = dC[(size_t)(l0+i)*8192 + hc0 + tx];
    __syncthreads();
    for (int i = threadIdx.y; i < 32; i += 8)
        DCT[(size_t)(hc0+i)*2048 + l0 + tx] = tile[tx][i];
}

// ---------------- Cauchy + Woodbury -> k_f ---------------- (fast-rcp only change)
__global__ __launch_bounds__(256) void cauchy_k(
                         const float* __restrict__ log_dt, const float* __restrict__ B_ri,
                         const float* __restrict__ P_ri, const float* __restrict__ C_ri,
                         const float* __restrict__ ivw, const float* __restrict__ wimag,
                         const float4* __restrict__ ZT, float2* __restrict__ KF)
{
    const int h  = blockIdx.y;
    const int c0 = blockIdx.z * 8;
    const int l  = blockIdx.x*256 + (int)threadIdx.x;
    __shared__ float wre[32], wim[32], bre[32], bim[32], ppre[32], ppim[32];
    __shared__ float cre[8][32], cim[8][32];
    __shared__ float dt_sh;
    if (threadIdx.x < 32){
        int n = threadIdx.x;
        float dt = expf(log_dt[h]);
        wre[n] = -expf(ivw[h*32+n]) * dt;
        wim[n] = wimag[h*32+n] * dt;
        bre[n] = B_ri[(h*32+n)*2+0];
        bim[n] = B_ri[(h*32+n)*2+1];
        ppre[n] = P_ri[(h*32+n)*2+0];
        ppim[n] = P_ri[(h*32+n)*2+1];
        if (n == 0) dt_sh = dt;
    }
    {
        int i = threadIdx.x;
        int cc = i >> 5, n = i & 31;
        size_t base = (((size_t)(c0+cc)*256 + h)*32 + n)*2;
        cre[cc][n] = C_ri[base+0];
        cim[cc][n] = C_ri[base+1];
    }
    __syncthreads();
    if (l >= LF) return;

    float4 zt = ZT[l];
    const float zx = zt.x, zy = zt.y;
    float r0x[9], r0y[9], r1x[9], r1y[9];
    #pragma unroll
    for (int j=0;j<9;++j){ r0x[j]=0.f; r0y[j]=0.f; r1x[j]=0.f; r1y[j]=0.f; }

    #pragma unroll 1
    for (int n=0; n<32; ++n){
        float wr = wre[n], wi = wim[n];
        float dx = zx - wr;
        float dy = zy - wi;
        float ey = zy + wi;
        float ip = frcp(dx*dx + dy*dy);
        float im = frcp(dx*dx + ey*ey);
        float cpx = dx*ip, cpy = -dy*ip;
        float cmx = dx*im, cmy = -ey*im;
        float br = bre[n], bi = bim[n];
        float t0x = br*cpx - bi*cpy, t0y = br*cpy + bi*cpx;
        float t1x = br*cmx + bi*cmy, t1y = br*cmy - bi*cmx;
        float pr = ppre[n], pi = ppim[n];
        float t2x = pr*cpx - pi*cpy, t2y = pr*cpy + pi*cpx;
        float t3x = pr*cmx + pi*cmy, t3y = pr*cmy - pi*cmx;
        float u0 = t0x+t1x, v0 = t1y-t0y, s0 = t0y+t1y, q0 = t0x-t1x;
        float u1 = t2x+t3x, v1 = t3y-t2y, s1 = t2y+t3y, q1 = t2x-t3x;
        #pragma unroll
        for (int j=0;j<8;++j){
            float a = cre[j][n], b = cim[j][n];
            r0x[j] = fmaf(a,u0, fmaf(b,v0, r0x[j]));
            r0y[j] = fmaf(a,s0, fmaf(b,q0, r0y[j]));
            r1x[j] = fmaf(a,u1, fmaf(b,v1, r1x[j]));
            r1y[j] = fmaf(a,s1, fmaf(b,q1, r1y[j]));
        }
        r0x[8] = fmaf(pr,u0, fmaf(-pi,v0, r0x[8]));
        r0y[8] = fmaf(pr,s0, fmaf(-pi,q0, r0y[8]));
        r1x[8] = fmaf(pr,u1, fmaf(-pi,v1, r1x[8]));
        r1y[8] = fmaf(pr,s1, fmaf(-pi,q1, r1y[8]));
    }

    float dt = dt_sh;
    #pragma unroll
    for (int j=0;j<9;++j){ r0x[j]*=dt; r0y[j]*=dt; r1x[j]*=dt; r1y[j]*=dt; }
    float drr = 1.0f + r1x[8], dii = r1y[8];
    float idn = frcp(drr*drr + dii*dii);
    float gx = (r0x[8]*drr + r0y[8]*dii)*idn;
    float gy = (r0y[8]*drr - r0x[8]*dii)*idn;
    float tfx = zt.z, tfy = zt.w;
    #pragma unroll
    for (int j=0;j<8;++j){
        float kr = r0x[j] - (gx*r1x[j] - gy*r1y[j]);
        float ki = r0y[j] - (gx*r1y[j] + gy*r1x[j]);
        KF[((size_t)((c0+j)*256+h))*1026 + l] = make_float2(kr*tfx - ki*tfy, kr*tfy + ki*tfx);
    }
}

// ---------------- radix-8 butterfly on registers (post-twiddle) ----------------
template<bool INV>
__device__ __forceinline__ void bfly8(float2 v[8]){
    float2 e0,e1,e2,e3,o0,o1,o2,o3;
    {   // DFT4 of v0,v2,v4,v6
        float t0x=v[0].x+v[4].x, t0y=v[0].y+v[4].y;
        float t1x=v[0].x-v[4].x, t1y=v[0].y-v[4].y;
        float t2x=v[2].x+v[6].x, t2y=v[2].y+v[6].y;
        float t3x=v[2].x-v[6].x, t3y=v[2].y-v[6].y;
        e0 = make_float2(t0x+t2x, t0y+t2y);
        e2 = make_float2(t0x-t2x, t0y-t2y);
        if (!INV){ e1 = make_float2(t1x+t3y, t1y-t3x); e3 = make_float2(t1x-t3y, t1y+t3x); }
        else     { e1 = make_float2(t1x-t3y, t1y+t3x); e3 = make_float2(t1x+t3y, t1y-t3x); }
    }
    {   // DFT4 of v1,v3,v5,v7
        float t0x=v[1].x+v[5].x, t0y=v[1].y+v[5].y;
        float t1x=v[1].x-v[5].x, t1y=v[1].y-v[5].y;
        float t2x=v[3].x+v[7].x, t2y=v[3].y+v[7].y;
        float t3x=v[3].x-v[7].x, t3y=v[3].y-v[7].y;
        o0 = make_float2(t0x+t2x, t0y+t2y);
        o2 = make_float2(t0x-t2x, t0y-t2y);
        if (!INV){ o1 = make_float2(t1x+t3y, t1y-t3x); o3 = make_float2(t1x-t3y, t1y+t3x); }
        else     { o1 = make_float2(t1x-t3y, t1y+t3x); o3 = make_float2(t1x+t3y, t1y-t3x); }
    }
    const float RC = 0.70710678118654752f;
    float2 w1o1, w2o2, w3o3;
    if (!INV){
        w1o1 = make_float2(RC*(o1.x+o1.y), RC*(o1.y-o1.x));    // (1-i)/sqrt2
        w2o2 = make_float2(o2.y, -o2.x);                       // -i
        w3o3 = make_float2(RC*(o3.y-o3.x), RC*(-o3.x-o3.y));   // -(1+i)/sqrt2
    } else {
        w1o1 = make_float2(RC*(o1.x-o1.y), RC*(o1.y+o1.x));    // (1+i)/sqrt2
        w2o2 = make_float2(-o2.y, o2.x);                       // i
        w3o3 = make_float2(RC*(-o3.x-o3.y), RC*(o3.x-o3.y));   // (-1+i)/sqrt2
    }
    v[0] = make_float2(e0.x+o0.x,   e0.y+o0.y);
    v[1] = make_float2(e1.x+w1o1.x, e1.y+w1o1.y);
    v[2] = make_float2(e2.x+w2o2.x, e2.y+w2o2.y);
    v[3] = make_float2(e3.x+w3o3.x, e3.y+w3o3.y);
    v[4] = make_float2(e0.x-o0.x,   e0.y-o0.y);
    v[5] = make_float2(e1.x-w1o1.x, e1.y-w1o1.y);
    v[6] = make_float2(e2.x-w2o2.x, e2.y-w2o2.y);
    v[7] = make_float2(e3.x-w3o3.x, e3.y-w3o3.y);
}

// ---------------- fft2048 = radix-4 (cross-wave) x 512-FFT (wave-local) ------
// Round-8 core change. 2048 = 4 groups x 512. Stage A: each thread's v[8]
// (elements t+256m) forms TWO stride-512 radix-4 butterflies (r=t, r=t+256)
// entirely in registers; post-twiddle e^{-+2pi i g r/2048}; scatter to A[g][r].
// One barrier. Then wave w runs the 512-point FFT of group w ALONE: 3 radix-8
// stages with only s_waitcnt lgkmcnt(0) between them (wave64 lockstep => own
// ds writes visible after waitcnt; no cross-wave data). One final barrier.
// Barriers/FFT: 4 -> 2, and ~75% of the work is barrier-free so the 8 resident
// waves drift and hide each other's LDS/trans latency.
// Output: bin 4s+g at B[gslot(g,s)] (use binslot(j) to read bin j).
// Twiddles: 1 v_sin/v_cos pair + cmul power chain per stage (trans 40 -> 8).
template<bool INV>
__device__ __forceinline__ void fftR(float2 v[8], float2* __restrict__ A, float2* __restrict__ B){
    const int t = threadIdx.x;
    // ---- stage A: regs -> A (cross-thread scatter); no entry barrier needed:
    // A was last read by the previous fftR's g3 stage, which completed before
    // the previous final __syncthreads; consumers since then only read B.
    #pragma unroll
    for (int half=0; half<2; ++half){
        int r = t + half*256;
        float2 x0=v[half], x1=v[2+half], x2=v[4+half], x3=v[6+half];
        float t0x=x0.x+x2.x, t0y=x0.y+x2.y;
        float t1x=x0.x-x2.x, t1y=x0.y-x2.y;
        float t2x=x1.x+x3.x, t2y=x1.y+x3.y;
        float t3x=x1.x-x3.x, t3y=x1.y-x3.y;
        float2 y0 = make_float2(t0x+t2x, t0y+t2y);
        float2 y2 = make_float2(t0x-t2x, t0y-t2y);
        float2 y1, y3;
        if (!INV){ y1 = make_float2(t1x+t3y, t1y-t3x); y3 = make_float2(t1x-t3y, t1y+t3x); }
        else     { y1 = make_float2(t1x-t3y, t1y+t3x); y3 = make_float2(t1x+t3y, t1y-t3x); }
        float2 w1 = twid((float)r * (1.0f/2048.0f));
        if (INV) w1.y = -w1.y;
        float2 w2 = cmulf(w1,w1);
        float2 w3 = cmulf(w2,w1);
        A[gslot(0,r)] = y0;
        A[gslot(1,r)] = cmulf(y1,w1);
        A[gslot(2,r)] = cmulf(y2,w2);
        A[gslot(3,r)] = cmulf(y3,w3);
    }
    __syncthreads();
    const int w = t >> 6, l = t & 63;
    // ---- g1: NS=1, A -> B (wave-local) ----
    {
        float2 u[8];
        #pragma unroll
        for (int m=0;m<8;++m) u[m] = A[gslot(w, l + 64*m)];
        bfly8<INV>(u);
        #pragma unroll
        for (int q=0;q<8;++q) B[gslot(w, 8*l+q)] = u[q];
    }
    lds_fence();
    // ---- g2: NS=8, B -> A (wave-local) ----
    {
        float2 u[8];
        #pragma unroll
        for (int m=0;m<8;++m) u[m] = B[gslot(w, l + 64*m)];
        int jm = l & 7;
        float2 w1 = twid((float)jm * (1.0f/64.0f));
        if (INV) w1.y = -w1.y;
        float2 wc = w1;
        #pragma unroll
        for (int m=1;m<8;++m){ u[m] = cmulf(u[m], wc); if (m<7) wc = cmulf(wc, w1); }
        bfly8<INV>(u);
        int d = ((l - jm) << 3) + jm;
        #pragma unroll
        for (int q=0;q<8;++q) A[gslot(w, d + q*8)] = u[q];
    }
    lds_fence();
    // ---- g3: NS=64, A -> B (wave-local) ----
    {
        float2 u[8];
        #pragma unroll
        for (int m=0;m<8;++m) u[m] = A[gslot(w, l + 64*m)];
        float2 w1 = twid((float)l * (1.0f/512.0f));
        if (INV) w1.y = -w1.y;
        float2 wc = w1;
        #pragma unroll
        for (int m=1;m<8;++m){ u[m] = cmulf(u[m], wc); if (m<7) wc = cmulf(wc, w1); }
        bfly8<INV>(u);
        #pragma unroll
        for (int q=0;q<8;++q) B[gslot(w, l + q*64)] = u[q];
    }
    __syncthreads();
}

// ---------------- kernel C2: pd rows -> packed even/odd 4096-bin spectra ---------
__global__ __launch_bounds__(256,2) void kernC2(const float* __restrict__ pd,
                                                float2* __restrict__ PDE, float2* __restrict__ PDO){
    __shared__ float2 A[4*GS], Bb[4*GS];
    const int t = threadIdx.x;
    const int h = blockIdx.x;
    const float* p0 = pd + (size_t)h * 2048;
    const float* p1 = pd + (size_t)(256 + h) * 2048;
    float2 z[8], v[8];
    #pragma unroll
    for (int m=0;m<8;++m){
        int j = t + m*256;
        z[m] = make_float2(p0[j], p1[j]);
        v[m] = z[m];
    }
    fftR<false>(v, A, Bb);                    // bins in Bb (permuted layout)
    float2* oe = PDE + (size_t)h * 2048;
    #pragma unroll
    for (int m=0;m<8;++m){ int j = t + m*256; oe[j] = Bb[binslot(j)]; }
    #pragma unroll
    for (int m=0;m<8;++m){
        int j = t + m*256;
        v[m] = cmulf(twid((float)j * (1.0f/4096.0f)), z[m]);   // * e^{-2pi i j/4096}
    }
    fftR<false>(v, A, Bb);
    float2* oo = PDO + (size_t)h * 2048;
    #pragma unroll
    for (int m=0;m<8;++m){ int j = t + m*256; oo[j] = Bb[binslot(j)]; }
}

// ---------------- fused kernel F v8 ----------------
// Plumbing identical to round 7 (pde_s/pdo_s staged, grid y=2, 2 blk/CU,
// launch_bounds(256,2) = the only non-spilling config, channel pairing).
// FFT engine swapped for the 2-barrier wave-local fftR above. All loader /
// consumer loops keep j = t+256m; only post-FFT reads use binslot(j).
__global__ __launch_bounds__(256,2) void kernF(const float2* __restrict__ KFb,
                                               const float2* __restrict__ PDE,
                                               const float2* __restrict__ PDO,
                                               const float* __restrict__ DCT,
                                               float* __restrict__ out){
    __shared__ float2 A[4*GS], Bb[4*GS];
    __shared__ float2 pde_s[2048], pdo_s[2048];
    const int t = threadIdx.x;
    const int h = blockIdx.x;
    const int cq = blockIdx.y;                 // 0..1, 16 channels (8 pairs) each
    {
        const float2* pe = PDE + (size_t)h * 2048;
        const float2* po = PDO + (size_t)h * 2048;
        #pragma unroll
        for (int m=0;m<8;++m){
            int j = t + m*256;
            pde_s[j] = pe[j];
            pdo_s[j] = po[j];
        }
    }
    float accr[8], acci[8];
    #pragma unroll
    for (int m=0;m<8;++m){ accr[m]=0.f; acci[m]=0.f; }
    __syncthreads();                            // pde_s/pdo_s visible to all

    #pragma unroll 1
    for (int pp=0; pp<8; ++pp){
        const int ca = cq*16 + pp*2;
        const float2* ra = KFb + (size_t)(ca*256+h)*1026;
        const float2* rb = KFb + (size_t)((ca+1)*256+h)*1026;

        // prefetch dct for both channels (consumed after FFTs; hides latency)
        float dcva[8], dcvb[8];
        {
            const float* dcta = DCT + (size_t)(h*32 + ca) * 2048;
            const float* dctb = dcta + 2048;
            #pragma unroll
            for (int m=0;m<8;++m){
                int j = t + m*256;
                dcva[m] = dcta[j] * (1.0f/4096.0f);
                dcvb[m] = dctb[j] * (1.0f/4096.0f);
            }
        }
        float2 v[8];

        // ---- Phase E, channel a: ifft(pde * Herm(kf_a)); accumulate ----
        #pragma unroll
        for (int m=0;m<8;++m){
            int j = t + m*256;
            float2 u;
            if (j <= 1024) u = ra[j];
            else { float2 w = ra[2048-j]; u = make_float2(w.x, -w.y); }  // Hermitian
            v[m] = cmulf(pde_s[j], u);
        }
        fftR<true>(v, A, Bb);
        #pragma unroll
        for (int m=0;m<8;++m){
            int j = t + m*256;
            float2 xe = Bb[binslot(j)];
            accr[m] = fmaf(xe.x, dcva[m], accr[m]);
            acci[m] = fmaf(xe.y, dcva[m], acci[m]);
        }
        // ---- Phase E, channel b ----
        #pragma unroll
        for (int m=0;m<8;++m){
            int j = t + m*256;
            float2 u;
            if (j <= 1024) u = rb[j];
            else { float2 w = rb[2048-j]; u = make_float2(w.x, -w.y); }
            v[m] = cmulf(pde_s[j], u);
        }
        fftR<true>(v, A, Bb);
        #pragma unroll
        for (int m=0;m<8;++m){
            int j = t + m*256;
            float2 xe = Bb[binslot(j)];
            accr[m] = fmaf(xe.x, dcvb[m], accr[m]);
            acci[m] = fmaf(xe.y, dcvb[m], acci[m]);
        }

        // ---- Phase O (paired): ifft(Herm_a + i*Herm_b) = 2048*(k_a + i*k_b) ----
        #pragma unroll
        for (int m=0;m<8;++m){
            int j = t + m*256;
            float2 va, vb;
            if (j <= 1024){ va = ra[j]; vb = rb[j]; }
            else {
                float2 u = ra[2048-j]; va = make_float2(u.x, -u.y);
                float2 w = rb[2048-j]; vb = make_float2(w.x, -w.y);
            }
            v[m] = make_float2(va.x - vb.y, va.y + vb.x);
        }
        fftR<true>(v, A, Bb);                  // packed k in Bb (sample n at binslot(n))
        // modulate (gather time-sample n = t+256m), feed Z-fft from regs
        #pragma unroll
        for (int m=0;m<8;++m){
            int j = t + m*256;
            float2 kk = Bb[binslot(j)];
            kk.x *= (1.0f/2048.0f); kk.y *= (1.0f/2048.0f);
            v[m] = cmulf(kk, twid((float)j * (1.0f/4096.0f)));   // * e^{-2pi i j/4096}
        }
        fftR<false>(v, A, Bb);                 // Z = K2odd_a + i*K2odd_b in Bb

        // unpack + products (cross reads of Bb, behind fftR's final sync)
        float2 pa[8], sb[8];
        #pragma unroll
        for (int m=0;m<8;++m){
            int j  = t + m*256;
            float2 z  = Bb[binslot(j)];
            float2 zm = Bb[binslot(2047 - j)];
            float2 Ka = make_float2(0.5f*(z.x + zm.x), 0.5f*(z.y - zm.y));
            float2 Kb = make_float2(0.5f*(z.y + zm.y), 0.5f*(zm.x - z.x));
            float2 pov = pdo_s[j];
            pa[m] = cmulf(pov, Ka);
            sb[m] = cmulf(pov, Kb);
        }
        // ifft channel a
        fftR<true>(pa, A, Bb);
        #pragma unroll
        for (int m=0;m<8;++m){
            int j = t + m*256;
            float2 w = twid((float)j * (1.0f/4096.0f));
            float2 ee = make_float2(w.x, -w.y);      // e^{+2pi i j/4096}
            float2 rot = cmulf(ee, Bb[binslot(j)]);
            accr[m] = fmaf(rot.x, dcva[m], accr[m]);
            acci[m] = fmaf(rot.y, dcva[m], acci[m]);
        }
        // ifft channel b from held regs
        fftR<true>(sb, A, Bb);
        #pragma unroll
        for (int m=0;m<8;++m){
            int j = t + m*256;
            float2 w = twid((float)j * (1.0f/4096.0f));
            float2 ee = make_float2(w.x, -w.y);
            float2 rot = cmulf(ee, Bb[binslot(j)]);
            accr[m] = fmaf(rot.x, dcvb[m], accr[m]);
            acci[m] = fmaf(rot.y, dcvb[m], acci[m]);
        }
    }
    #pragma unroll
    for (int m=0;m<8;++m){
        int j = t + m*256;
        atomicAdd(&out[((size_t)h)*2048 + j],       accr[m]);   // batch 0 (Re)
        atomicAdd(&out[((size_t)(256+h))*2048 + j], acci[m]);   // batch 1 (Im)
    }
}

extern "C" void kernel_launch(void* const* d_in, const int* in_sizes, int n_in,
                              void* d_out, int out_size, void* d_ws, size_t ws_size,
                              hipStream_t stream) {
    const float* log_dt = (const float*)d_in[0];
    const float* B_ri   = (const float*)d_in[1];
    const float* P_ri   = (const float*)d_in[2];
    const float* C_ri   = (const float*)d_in[3];
    const float* ivw    = (const float*)d_in[4];
    const float* wimag  = (const float*)d_in[5];
    const float* dC     = (const float*)d_in[6];
    const float* pd     = (const float*)d_in[7];

    char* ws = (char*)d_ws;
    float4* ZT  = (float4*)(ws + OFF_ZT);
    float2* KF  = (float2*)(ws + OFF_KF);
    float2* PDE = (float2*)(ws + OFF_PDF);
    float2* PDO = (float2*)(ws + OFF_PDF + 256*2048*sizeof(float2));
    float*  DCT = (float*) (ws + OFF_DCT);
    float* out = (float*)d_out;

    hipMemsetAsync(out, 0, (size_t)out_size * sizeof(float), stream);
    initk<<<5, 256, 0, stream>>>(ZT);
    transpose_dC<<<dim3(256,64), dim3(32,8), 0, stream>>>(dC, DCT);
    cauchy_k<<<dim3(5,256,4), 256, 0, stream>>>(log_dt, B_ri, P_ri, C_ri, ivw, wimag, ZT, KF);
    kernC2<<<256, 256, 0, stream>>>(pd, PDE, PDO);
    kernF<<<dim3(256,2), 256, 0, stream>>>((const float2*)KF, PDE, PDO, DCT, out);
}